// Round 10
// baseline (2352.518 us; speedup 1.0000x reference)
//
#include <hip/hip_runtime.h>
#include <hip/hip_bf16.h>
#include <math.h>

// ---------------- problem constants ----------------
constexpr int T_STEPS = 256;
constexpr int HDIM    = 1024;
constexpr int EDIM    = 512;
constexpr int VDIM    = 32000;

#define RG     128          // recurrence workgroups (spread over chip)
#define RROWS  8            // rows owned per WG
#define NBN    125          // 32000 / 256 n-tiles
#define NCH    4            // m-chunks of 64 rows
#define GEMMB  (NBN * NCH)  // 500 gemm blocks

// ---------------- ws layout (float offsets) ----------------
constexpr size_t WS_BZ     = 0;                                   // [T][H]
constexpr size_t WS_BR     = WS_BZ + (size_t)T_STEPS * HDIM;      // [T][H]
constexpr size_t WS_A      = WS_BR + (size_t)T_STEPS * HDIM;      // [T][H]
constexpr size_t WS_HPACK  = WS_A  + (size_t)T_STEPS * HDIM;      // ull[(T+1)][H]: (tag<<32)|bits
constexpr size_t WS_RHPACK = WS_HPACK + (size_t)2 * (T_STEPS + 1) * HDIM; // ull[H]
constexpr size_t WS_HSEQ   = WS_BZ;                               // fp32 overlay (argmax refine)

typedef __attribute__((ext_vector_type(8))) short short8;
typedef __attribute__((ext_vector_type(4))) float f32x4;

__device__ __forceinline__ float sigmoidf_(float x) { return 1.0f / (1.0f + __expf(-x)); }

__device__ __forceinline__ unsigned long long pack_tv(int tag, float v) {
  return ((unsigned long long)(unsigned)tag << 32) | (unsigned long long)__float_as_uint(v);
}

__device__ __forceinline__ unsigned short f2bf_fast(float f) {  // compiler-fusable RNE cast
  __hip_bfloat16 b = __float2bfloat16(f);
  return *reinterpret_cast<unsigned short*>(&b);
}

// ---------------- pre: init tags + h0 (blocks >=192) and e-projections (blocks <192) ----------------
__global__ __launch_bounds__(256) void k_pre(
    const float* __restrict__ enc,
    const int* __restrict__ tokens, const float* __restrict__ emb,
    const float* __restrict__ wzx, const float* __restrict__ wrx, const float* __restrict__ whx,
    const float* __restrict__ bzx, const float* __restrict__ bzh,
    const float* __restrict__ brx, const float* __restrict__ brh,
    const float* __restrict__ bhx, const float* __restrict__ bhh,
    float* __restrict__ ws) {
  const int tid = threadIdx.x;
  if (blockIdx.x >= 192) {
    // ---- init path (258 blocks): ws NOT re-poisoned between replays — clear tags ----
    unsigned long long* hpack  = (unsigned long long*)(ws + WS_HPACK);
    unsigned long long* rhpack = (unsigned long long*)(ws + WS_RHPACK);
    const int b2 = blockIdx.x - 192;
    if (b2 == 0) {
      for (int i = tid; i < HDIM; i += 256) hpack[i] = pack_tv(1, enc[i]);
    } else if (b2 <= T_STEPS) {
      unsigned long long* row = hpack + (size_t)b2 * HDIM;
      for (int i = tid; i < HDIM; i += 256) row[i] = 0ULL;
    } else {
      for (int i = tid; i < HDIM; i += 256) rhpack[i] = 0ULL;
    }
    return;
  }
  // ---- xproj path (192 blocks) ----
  __shared__ __align__(16) float es[16][EDIM];   // 32 KiB
  const int b   = blockIdx.x;
  const int t0  = (b & 15) * 16;
  const int c   = b >> 4;                 // 0..11
  {
    int row = tid >> 4;
    int kc  = (tid & 15) * 32;
    int tok = tokens[t0 + row];
    const float4* ep = (const float4*)(emb + (size_t)tok * EDIM + kc);
    float4* dst = (float4*)&es[row][kc];
    #pragma unroll
    for (int q = 0; q < 8; q++) dst[q] = ep[q];
  }
  __syncthreads();

  const int mat = c >> 2;
  const int j   = (c & 3) * 256 + tid;
  const float* W; const float* b1; const float* b2p; float* Xout;
  if (mat == 0)      { W = wzx; b1 = bzx; b2p = bzh; Xout = ws + WS_BZ; }
  else if (mat == 1) { W = wrx; b1 = brx; b2p = brh; Xout = ws + WS_BR; }
  else               { W = whx; b1 = bhx; b2p = bhh; Xout = ws + WS_A;  }

  const float4* wp = (const float4*)(W + (size_t)j * EDIM);
  const float bias = b1[j] + b2p[j];
  float acc[16];
  #pragma unroll
  for (int tt = 0; tt < 16; tt++) acc[tt] = 0.0f;

  for (int k4 = 0; k4 < EDIM / 4; k4++) {
    float4 w = wp[k4];
    #pragma unroll
    for (int tt = 0; tt < 16; tt++) {
      float4 e4 = *(const float4*)&es[tt][k4 * 4];
      acc[tt] += w.x * e4.x + w.y * e4.y + w.z * e4.z + w.w * e4.w;
    }
  }
  #pragma unroll
  for (int tt = 0; tt < 16; tt++)
    Xout[(size_t)(t0 + tt) * HDIM + j] = acc[tt] + bias;
}

// ---------------- fused main: recurrence (blocks 0..127) + overlapped logits GEMM ----------------
// Recurrence = r3's proven structure (sentinel poll, relaxed agent atomics), unchanged.
// GEMM blocks read A directly from hpack (low 32 bits = h fp32), readiness = the tags
// themselves (monotone; tag at row 64(c+1) >= 64(c+1)+1 for all 128 producers => all
// hpack rows <= 64(c+1) are fully published). Both sides use the same agent-atomic
// primitives proven cross-XCD-coherent in r2-r9.
__global__ __launch_bounds__(256, 4) void k_main(
    const float* __restrict__ wzh, const float* __restrict__ wrh, const float* __restrict__ whh,
    const float* __restrict__ outw, const float* __restrict__ outb,
    float* __restrict__ ws, float* __restrict__ out) {
  const int tid  = threadIdx.x;
  const int lane = tid & 63;
  const int wv   = tid >> 6;
  unsigned long long* hpack  = (unsigned long long*)(ws + WS_HPACK);
  unsigned long long* rhpack = (unsigned long long*)(ws + WS_RHPACK);

  if (blockIdx.x < RG) {
    // ================= recurrence path =================
    __builtin_amdgcn_s_setprio(1);   // T5: keep critical-path wave favored over GEMM waves
    const int g  = blockIdx.x;
    const float* Bz = ws + WS_BZ;
    const float* Br = ws + WS_BR;
    const float* Aa = ws + WS_A;
    float* hseq = ws + WS_HSEQ;

    const int j0 = 4 * tid;          // this thread's h-slice [j0, j0+4) — single producer WG
    const int r0 = g * RROWS;        // this WG's row base

    float4 wz[RROWS], wr[RROWS], wh[RROWS];   // 96 register-resident weights
    #pragma unroll
    for (int k = 0; k < RROWS; k++) {
      wz[k] = *(const float4*)(wzh + (size_t)(r0 + k) * HDIM + j0);
      wr[k] = *(const float4*)(wrh + (size_t)(r0 + k) * HDIM + j0);
      wh[k] = *(const float4*)(whh + (size_t)(r0 + k) * HDIM + j0);
    }

    __shared__ float redA[4][2 * RROWS];
    __shared__ float redB[4][RROWS];
    __shared__ float zs[RROWS];
    __shared__ float hloc[RROWS];
    if (tid < RROWS)
      hloc[tid] = __uint_as_float((unsigned)hpack[r0 + tid]);  // h0 from k_pre
    __syncthreads();

    for (int t = 0; t < T_STEPS; t++) {
      float bz_pre = 0.0f, br_pre = 0.0f, a_pre = 0.0f;
      if (tid < RROWS) {
        bz_pre = Bz[(size_t)t * HDIM + r0 + tid];
        a_pre  = Aa[(size_t)t * HDIM + r0 + tid];
      } else if (tid < 2 * RROWS) {
        br_pre = Br[(size_t)t * HDIM + r0 + (tid - RROWS)];
      }
      const unsigned long long ex = (unsigned long long)(unsigned)(t + 1);

      // ---- round A: z, r, publish r*h ----
      float hv0, hv1, hv2, hv3;
      {
        const unsigned long long* hp = hpack + (size_t)t * HDIM + j0;
        unsigned long long w0, w1, w2, w3;
        int it = 0;
        for (;;) {   // sentinel poll: word 0 only
          w0 = __hip_atomic_load(hp + 0, __ATOMIC_RELAXED, __HIP_MEMORY_SCOPE_AGENT);
          if ((w0 >> 32) == ex) break;
          if (++it > (1 << 20)) break;
          __builtin_amdgcn_s_sleep(2);
        }
        for (;;) {   // remaining 3 words: same producer wave-store, nearly always ready
          w1 = __hip_atomic_load(hp + 1, __ATOMIC_RELAXED, __HIP_MEMORY_SCOPE_AGENT);
          w2 = __hip_atomic_load(hp + 2, __ATOMIC_RELAXED, __HIP_MEMORY_SCOPE_AGENT);
          w3 = __hip_atomic_load(hp + 3, __ATOMIC_RELAXED, __HIP_MEMORY_SCOPE_AGENT);
          if (((w1 >> 32) == ex) & ((w2 >> 32) == ex) & ((w3 >> 32) == ex)) break;
          if (++it > (1 << 20)) break;
          __builtin_amdgcn_s_sleep(1);
        }
        hv0 = __uint_as_float((unsigned)w0);
        hv1 = __uint_as_float((unsigned)w1);
        hv2 = __uint_as_float((unsigned)w2);
        hv3 = __uint_as_float((unsigned)w3);
      }

      float pz[RROWS], pr[RROWS];
      #pragma unroll
      for (int k = 0; k < RROWS; k++) {
        pz[k] = wz[k].x * hv0 + wz[k].y * hv1 + wz[k].z * hv2 + wz[k].w * hv3;
        pr[k] = wr[k].x * hv0 + wr[k].y * hv1 + wr[k].z * hv2 + wr[k].w * hv3;
      }
      #pragma unroll
      for (int m = 32; m >= 1; m >>= 1) {
        #pragma unroll
        for (int k = 0; k < RROWS; k++) {
          pz[k] += __shfl_xor(pz[k], m);
          pr[k] += __shfl_xor(pr[k], m);
        }
      }
      if (lane == 0) {
        #pragma unroll
        for (int k = 0; k < RROWS; k++) { redA[wv][k] = pz[k]; redA[wv][RROWS + k] = pr[k]; }
      }
      __syncthreads();
      if (tid < RROWS) {
        float u = redA[0][tid] + redA[1][tid] + redA[2][tid] + redA[3][tid];
        zs[tid] = sigmoidf_(bz_pre + u);
      } else if (tid < 2 * RROWS) {
        int k = tid - RROWS;
        float u = redA[0][tid] + redA[1][tid] + redA[2][tid] + redA[3][tid];
        float r = sigmoidf_(br_pre + u);
        float rh = r * hloc[k];
        __hip_atomic_store(&rhpack[r0 + k], pack_tv(t + 1, rh),
                           __ATOMIC_RELAXED, __HIP_MEMORY_SCOPE_AGENT);
      }

      // ---- round B: v = whh@(r*h), h_new ----
      float rv0, rv1, rv2, rv3;
      {
        const unsigned long long* rp = rhpack + j0;
        unsigned long long w0, w1, w2, w3;
        int it = 0;
        for (;;) {
          w0 = __hip_atomic_load(rp + 0, __ATOMIC_RELAXED, __HIP_MEMORY_SCOPE_AGENT);
          if ((w0 >> 32) == ex) break;
          if (++it > (1 << 20)) break;
          __builtin_amdgcn_s_sleep(2);
        }
        for (;;) {
          w1 = __hip_atomic_load(rp + 1, __ATOMIC_RELAXED, __HIP_MEMORY_SCOPE_AGENT);
          w2 = __hip_atomic_load(rp + 2, __ATOMIC_RELAXED, __HIP_MEMORY_SCOPE_AGENT);
          w3 = __hip_atomic_load(rp + 3, __ATOMIC_RELAXED, __HIP_MEMORY_SCOPE_AGENT);
          if (((w1 >> 32) == ex) & ((w2 >> 32) == ex) & ((w3 >> 32) == ex)) break;
          if (++it > (1 << 20)) break;
          __builtin_amdgcn_s_sleep(1);
        }
        rv0 = __uint_as_float((unsigned)w0);
        rv1 = __uint_as_float((unsigned)w1);
        rv2 = __uint_as_float((unsigned)w2);
        rv3 = __uint_as_float((unsigned)w3);
      }

      float ph[RROWS];
      #pragma unroll
      for (int k = 0; k < RROWS; k++)
        ph[k] = wh[k].x * rv0 + wh[k].y * rv1 + wh[k].z * rv2 + wh[k].w * rv3;
      #pragma unroll
      for (int m = 32; m >= 1; m >>= 1) {
        #pragma unroll
        for (int k = 0; k < RROWS; k++) ph[k] += __shfl_xor(ph[k], m);
      }
      if (lane == 0) {
        #pragma unroll
        for (int k = 0; k < RROWS; k++) redB[wv][k] = ph[k];
      }
      __syncthreads();
      if (tid < RROWS) {
        float v  = redB[0][tid] + redB[1][tid] + redB[2][tid] + redB[3][tid];
        float z  = zs[tid];
        float hk = hloc[tid];
        float hp_ = tanhf(a_pre + v);
        float hn = (1.0f - z) * hk + z * hp_;
        hloc[tid] = hn;
        __hip_atomic_store(&hpack[(size_t)(t + 1) * HDIM + r0 + tid], pack_tv(t + 2, hn),
                           __ATOMIC_RELAXED, __HIP_MEMORY_SCOPE_AGENT);
        hseq[(size_t)t * HDIM + r0 + tid] = hn;   // fp32 (argmax refine; read after kernel end)
      }
    }
    return;
  }

  // ================= overlapped GEMM path =================
  // block b: chunk c (64 m-rows) x n-tile nb (256 cols). Wave wv: 64x64 sub-tile.
  const int b  = blockIdx.x - RG;          // 0..499
  const int c  = b / NBN;
  const int nb = b - c * NBN;
  const int n0 = nb * 256;
  const int m0 = c * 64;

  // readiness: tag at hpack[64(c+1)*H + g*8] >= 64(c+1)+1 for all 128 producers
  {
    const unsigned long long thr = ((unsigned long long)(unsigned)(64 * (c + 1) + 1)) << 32;
    const unsigned long long* prow = hpack + (size_t)(64 * (c + 1)) * HDIM;
    const int g = tid & 127;
    int it = 0;
    for (;;) {
      unsigned long long w = __hip_atomic_load(prow + (size_t)g * RROWS,
                                               __ATOMIC_RELAXED, __HIP_MEMORY_SCOPE_AGENT);
      int ok = (w >= thr) | (it > (1 << 17));
      if (__syncthreads_and(ok)) break;
      ++it;
      __builtin_amdgcn_s_sleep(32);   // coarse: readiness granularity is ~300us
    }
  }

  const int rA  = lane & 15;
  const int kg  = lane >> 4;
  const int nw0 = n0 + wv * 64;

  f32x4 acc[4][4];
  #pragma unroll
  for (int i = 0; i < 4; i++)
    #pragma unroll
    for (int j = 0; j < 4; j++) acc[i][j] = (f32x4){0.f, 0.f, 0.f, 0.f};

  for (int k0 = 0; k0 < HDIM; k0 += 32) {
    const int ks = k0 + kg * 8;
    short8 afr[4];
    #pragma unroll
    for (int mi = 0; mi < 4; mi++) {
      // logits row m = m0+mi*16+rA ; A[m][k] = h_{m+1}[k] = low32(hpack[(m+1)*H + k])
      const unsigned long long* ap = hpack + (size_t)(m0 + mi * 16 + rA + 1) * HDIM + ks;
      short8 s;
      #pragma unroll
      for (int e = 0; e < 8; e++) {
        unsigned long long w = __hip_atomic_load(ap + e, __ATOMIC_RELAXED, __HIP_MEMORY_SCOPE_AGENT);
        s[e] = (short)f2bf_fast(__uint_as_float((unsigned)w));
      }
      afr[mi] = s;
    }
    short8 bfr[4];
    #pragma unroll
    for (int nj = 0; nj < 4; nj++) {
      const float* bp = outw + (size_t)(nw0 + nj * 16 + rA) * HDIM + ks;
      float4 b0 = *(const float4*)(bp);
      float4 b1 = *(const float4*)(bp + 4);
      short8 s;
      s[0] = (short)f2bf_fast(b0.x); s[1] = (short)f2bf_fast(b0.y);
      s[2] = (short)f2bf_fast(b0.z); s[3] = (short)f2bf_fast(b0.w);
      s[4] = (short)f2bf_fast(b1.x); s[5] = (short)f2bf_fast(b1.y);
      s[6] = (short)f2bf_fast(b1.z); s[7] = (short)f2bf_fast(b1.w);
      bfr[nj] = s;
    }
    #pragma unroll
    for (int mi = 0; mi < 4; mi++)
      #pragma unroll
      for (int nj = 0; nj < 4; nj++)
        acc[mi][nj] = __builtin_amdgcn_mfma_f32_16x16x32_bf16(afr[mi], bfr[nj], acc[mi][nj], 0, 0, 0);
  }

  float bias[4];
  #pragma unroll
  for (int nj = 0; nj < 4; nj++) bias[nj] = outb[nw0 + nj * 16 + rA];
  #pragma unroll
  for (int mi = 0; mi < 4; mi++) {
    #pragma unroll
    for (int nj = 0; nj < 4; nj++) {
      #pragma unroll
      for (int r = 0; r < 4; r++) {
        int m = m0 + mi * 16 + kg * 4 + r;
        out[(size_t)m * VDIM + nw0 + nj * 16 + rA] = acc[mi][nj][r] + bias[nj];
      }
    }
  }
}

// ---------------- argmax with fp32 refinement ----------------
__global__ __launch_bounds__(256) void k_argmax(const float* __restrict__ logits,
                                                const float* __restrict__ hseqf,
                                                const float* __restrict__ outw,
                                                const float* __restrict__ outb,
                                                float* __restrict__ outids) {
  const int t = blockIdx.x;
  const int tid = threadIdx.x;
  const float* row = logits + (size_t)t * VDIM;

  float mx = -3.4e38f;
  for (int v = tid; v < VDIM; v += 256) mx = fmaxf(mx, row[v]);
  __shared__ float sm[256];
  sm[tid] = mx;
  __syncthreads();
  for (int s = 128; s > 0; s >>= 1) {
    if (tid < s) sm[tid] = fmaxf(sm[tid], sm[tid + s]);
    __syncthreads();
  }
  const float bmax = sm[0];
  __syncthreads();

  __shared__ int cand[64];
  __shared__ int cnt;
  if (tid == 0) cnt = 0;
  __syncthreads();
  const float cut = bmax - 0.25f;
  for (int v = tid; v < VDIM; v += 256) {
    if (row[v] >= cut) {
      int p = atomicAdd(&cnt, 1);
      if (p < 64) cand[p] = v;
    }
  }
  __syncthreads();
  int n = cnt < 64 ? cnt : 64;

  __shared__ float cval[64];
  if (tid < n) {
    int v = cand[tid];
    const float* w = outw + (size_t)v * HDIM;
    const float* h = hseqf + (size_t)t * HDIM;
    float s0 = 0.f, s1 = 0.f, s2 = 0.f, s3 = 0.f;
    for (int k = 0; k < HDIM; k += 4) {
      float4 wf = *(const float4*)(w + k);
      float4 hf = *(const float4*)(h + k);
      s0 += wf.x * hf.x; s1 += wf.y * hf.y; s2 += wf.z * hf.z; s3 += wf.w * hf.w;
    }
    cval[tid] = (s0 + s1) + (s2 + s3) + outb[v];
  }
  __syncthreads();
  if (tid == 0) {
    float best = -3.4e38f; int bi = 0x7FFFFFFF;
    for (int i = 0; i < n; i++) {
      float v = cval[i]; int id = cand[i];
      if (v > best || (v == best && id < bi)) { best = v; bi = id; }
    }
    outids[t] = (float)bi;
  }
}

// ---------------- launch ----------------
extern "C" void kernel_launch(void* const* d_in, const int* in_sizes, int n_in,
                              void* d_out, int out_size, void* d_ws, size_t ws_size,
                              hipStream_t stream) {
  (void)in_sizes; (void)n_in; (void)out_size; (void)ws_size;
  const float* enc    = (const float*)d_in[0];
  const int*   tokens = (const int*)d_in[1];
  const float* emb    = (const float*)d_in[2];
  const float* wzx_w  = (const float*)d_in[3];
  const float* wzx_b  = (const float*)d_in[4];
  const float* wrx_w  = (const float*)d_in[5];
  const float* wrx_b  = (const float*)d_in[6];
  const float* whx_w  = (const float*)d_in[7];
  const float* whx_b  = (const float*)d_in[8];
  const float* wzh_w  = (const float*)d_in[9];
  const float* wzh_b  = (const float*)d_in[10];
  const float* wrh_w  = (const float*)d_in[11];
  const float* wrh_b  = (const float*)d_in[12];
  const float* whh_w  = (const float*)d_in[13];
  const float* whh_b  = (const float*)d_in[14];
  const float* out_w  = (const float*)d_in[15];
  const float* out_b  = (const float*)d_in[16];
  float* ws  = (float*)d_ws;
  float* out = (float*)d_out;

  k_pre<<<dim3(192 + T_STEPS + 2), dim3(256), 0, stream>>>(
      enc, tokens, emb, wzx_w, wrx_w, whx_w,
      wzx_b, wzh_b, wrx_b, wrh_b, whx_b, whh_b, ws);
  k_main<<<dim3(RG + GEMMB), dim3(256), 0, stream>>>(wzh_w, wrh_w, whh_w,
                                                     out_w, out_b, ws, out);
  k_argmax<<<dim3(T_STEPS), dim3(256), 0, stream>>>(out, ws + WS_HSEQ, out_w, out_b,
                                                    out + (size_t)T_STEPS * VDIM);
}

// Round 11
// 1430.860 us; speedup vs baseline: 1.6441x; 1.6441x over previous
//
#include <hip/hip_runtime.h>
#include <hip/hip_bf16.h>
#include <math.h>

// ---------------- problem constants ----------------
constexpr int T_STEPS = 256;
constexpr int HDIM    = 1024;
constexpr int EDIM    = 512;
constexpr int VDIM    = 32000;

#define RG     128          // recurrence workgroups (spread over chip, 1/CU)
#define RROWS  8            // rows owned per WG
#define NBN    500          // 32000 / 64 n-tiles for k_gemm
#define TMSTR  512          // tilemax row stride (500 padded)

// ---------------- ws layout (float offsets) ----------------
// Overlays (proven by publish-chain ordering): hseq fp32 over BZ, hseq bf16 over BR.
constexpr size_t WS_BZ     = 0;                                   // [T][H]
constexpr size_t WS_BR     = WS_BZ + (size_t)T_STEPS * HDIM;      // [T][H]
constexpr size_t WS_A      = WS_BR + (size_t)T_STEPS * HDIM;      // [T][H]
constexpr size_t WS_HPACK  = WS_A  + (size_t)T_STEPS * HDIM;      // ull[(T+1)][H]: (tag<<32)|bits
constexpr size_t WS_RHPACK = WS_HPACK + (size_t)2 * (T_STEPS + 1) * HDIM; // ull[H]
constexpr size_t WS_TMAX   = WS_RHPACK + (size_t)2 * HDIM;        // float[256][TMSTR] per-tile row maxes
constexpr size_t WS_HSEQ   = WS_BZ;                               // fp32 overlay (argmax refine)
constexpr size_t WS_HSEQB  = WS_BR;                               // bf16 overlay (ushort*, GEMM A)

typedef __attribute__((ext_vector_type(8))) short short8;
typedef __attribute__((ext_vector_type(4))) float f32x4;

__device__ __forceinline__ float sigmoidf_(float x) { return 1.0f / (1.0f + __expf(-x)); }

__device__ __forceinline__ unsigned long long pack_tv(int tag, float v) {
  return ((unsigned long long)(unsigned)tag << 32) | (unsigned long long)__float_as_uint(v);
}

__device__ __forceinline__ unsigned short f2bf(float f) {   // RNE fp32 -> bf16 bits (manual)
  unsigned u = __float_as_uint(f);
  return (unsigned short)((u + 0x7FFFu + ((u >> 16) & 1u)) >> 16);
}

__device__ __forceinline__ unsigned short f2bf_fast(float f) {  // compiler-fusable RNE cast
  __hip_bfloat16 b = __float2bfloat16(f);
  return *reinterpret_cast<unsigned short*>(&b);
}

// ---------------- pre: init tags + h0 (blocks >=192) and e-projections (blocks <192) ----------------
__global__ __launch_bounds__(256) void k_pre(
    const float* __restrict__ enc,
    const int* __restrict__ tokens, const float* __restrict__ emb,
    const float* __restrict__ wzx, const float* __restrict__ wrx, const float* __restrict__ whx,
    const float* __restrict__ bzx, const float* __restrict__ bzh,
    const float* __restrict__ brx, const float* __restrict__ brh,
    const float* __restrict__ bhx, const float* __restrict__ bhh,
    float* __restrict__ ws) {
  const int tid = threadIdx.x;
  if (blockIdx.x >= 192) {
    // ---- init path: ws NOT re-poisoned between replays — clear tags every launch ----
    unsigned long long* hpack  = (unsigned long long*)(ws + WS_HPACK);
    unsigned long long* rhpack = (unsigned long long*)(ws + WS_RHPACK);
    const int b2 = blockIdx.x - 192;
    if (b2 == 0) {
      for (int i = tid; i < HDIM; i += 256) hpack[i] = pack_tv(1, enc[i]);
    } else if (b2 <= T_STEPS) {
      unsigned long long* row = hpack + (size_t)b2 * HDIM;
      for (int i = tid; i < HDIM; i += 256) row[i] = 0ULL;
    } else {
      for (int i = tid; i < HDIM; i += 256) rhpack[i] = 0ULL;
    }
    return;
  }
  // ---- xproj path (192 blocks): Bz/Br/A for all t ----
  __shared__ __align__(16) float es[16][EDIM];   // 32 KiB
  const int b   = blockIdx.x;
  const int t0  = (b & 15) * 16;
  const int c   = b >> 4;                 // 0..11
  {
    int row = tid >> 4;
    int kc  = (tid & 15) * 32;
    int tok = tokens[t0 + row];
    const float4* ep = (const float4*)(emb + (size_t)tok * EDIM + kc);
    float4* dst = (float4*)&es[row][kc];
    #pragma unroll
    for (int q = 0; q < 8; q++) dst[q] = ep[q];
  }
  __syncthreads();

  const int mat = c >> 2;
  const int j   = (c & 3) * 256 + tid;
  const float* W; const float* b1; const float* b2p; float* Xout;
  if (mat == 0)      { W = wzx; b1 = bzx; b2p = bzh; Xout = ws + WS_BZ; }
  else if (mat == 1) { W = wrx; b1 = brx; b2p = brh; Xout = ws + WS_BR; }
  else               { W = whx; b1 = bhx; b2p = bhh; Xout = ws + WS_A;  }

  const float4* wp = (const float4*)(W + (size_t)j * EDIM);
  const float bias = b1[j] + b2p[j];
  float acc[16];
  #pragma unroll
  for (int tt = 0; tt < 16; tt++) acc[tt] = 0.0f;

  for (int k4 = 0; k4 < EDIM / 4; k4++) {
    float4 w = wp[k4];
    #pragma unroll
    for (int tt = 0; tt < 16; tt++) {
      float4 e4 = *(const float4*)&es[tt][k4 * 4];
      acc[tt] += w.x * e4.x + w.y * e4.y + w.z * e4.z + w.w * e4.w;
    }
  }
  #pragma unroll
  for (int tt = 0; tt < 16; tt++)
    Xout[(size_t)(t0 + tt) * HDIM + j] = acc[tt] + bias;
}

// ---------------- persistent GRU recurrence — r3-EXACT (proven 1242us; sync floor) ----------------
__global__ __launch_bounds__(256) void k_recur(
    const float* __restrict__ wzh, const float* __restrict__ wrh, const float* __restrict__ whh,
    float* __restrict__ ws) {
  const int g    = blockIdx.x;
  const int tid  = threadIdx.x;
  const int lane = tid & 63;
  const int wv   = tid >> 6;
  const float* Bz = ws + WS_BZ;
  const float* Br = ws + WS_BR;
  const float* Aa = ws + WS_A;
  float* hseq = ws + WS_HSEQ;
  unsigned short* hseqb = (unsigned short*)(ws + WS_HSEQB);
  unsigned long long* hpack  = (unsigned long long*)(ws + WS_HPACK);
  unsigned long long* rhpack = (unsigned long long*)(ws + WS_RHPACK);

  const int j0 = 4 * tid;          // this thread's h-slice [j0, j0+4) — single producer WG
  const int r0 = g * RROWS;        // this WG's row base

  // register-resident weights: 3 x 8 rows x 4 cols = 96 floats
  float4 wz[RROWS], wr[RROWS], wh[RROWS];
  #pragma unroll
  for (int k = 0; k < RROWS; k++) {
    wz[k] = *(const float4*)(wzh + (size_t)(r0 + k) * HDIM + j0);
    wr[k] = *(const float4*)(wrh + (size_t)(r0 + k) * HDIM + j0);
    wh[k] = *(const float4*)(whh + (size_t)(r0 + k) * HDIM + j0);
  }

  __shared__ float redA[4][2 * RROWS];   // round A (z | r); separate from round B
  __shared__ float redB[4][RROWS];
  __shared__ float zs[RROWS];
  __shared__ float hloc[RROWS];
  if (tid < RROWS)
    hloc[tid] = __uint_as_float((unsigned)hpack[r0 + tid]);  // h0, written by k_pre
  __syncthreads();

  for (int t = 0; t < T_STEPS; t++) {
    float bz_pre = 0.0f, br_pre = 0.0f, a_pre = 0.0f;
    if (tid < RROWS) {
      bz_pre = Bz[(size_t)t * HDIM + r0 + tid];
      a_pre  = Aa[(size_t)t * HDIM + r0 + tid];
    } else if (tid < 2 * RROWS) {
      br_pre = Br[(size_t)t * HDIM + r0 + (tid - RROWS)];
    }
    const unsigned long long ex = (unsigned long long)(unsigned)(t + 1);

    // ================= round A: z, r, publish r*h =================
    float hv0, hv1, hv2, hv3;
    {
      const unsigned long long* hp = hpack + (size_t)t * HDIM + j0;
      unsigned long long w0, w1, w2, w3;
      int it = 0;
      for (;;) {   // sentinel poll: word 0 only
        w0 = __hip_atomic_load(hp + 0, __ATOMIC_RELAXED, __HIP_MEMORY_SCOPE_AGENT);
        if ((w0 >> 32) == ex) break;
        if (++it > (1 << 20)) break;
        __builtin_amdgcn_s_sleep(2);
      }
      for (;;) {   // remaining 3 words: same producer wave-store, nearly always ready
        w1 = __hip_atomic_load(hp + 1, __ATOMIC_RELAXED, __HIP_MEMORY_SCOPE_AGENT);
        w2 = __hip_atomic_load(hp + 2, __ATOMIC_RELAXED, __HIP_MEMORY_SCOPE_AGENT);
        w3 = __hip_atomic_load(hp + 3, __ATOMIC_RELAXED, __HIP_MEMORY_SCOPE_AGENT);
        if (((w1 >> 32) == ex) & ((w2 >> 32) == ex) & ((w3 >> 32) == ex)) break;
        if (++it > (1 << 20)) break;
        __builtin_amdgcn_s_sleep(1);
      }
      hv0 = __uint_as_float((unsigned)w0);
      hv1 = __uint_as_float((unsigned)w1);
      hv2 = __uint_as_float((unsigned)w2);
      hv3 = __uint_as_float((unsigned)w3);
    }

    float pz[RROWS], pr[RROWS];
    #pragma unroll
    for (int k = 0; k < RROWS; k++) {
      pz[k] = wz[k].x * hv0 + wz[k].y * hv1 + wz[k].z * hv2 + wz[k].w * hv3;
      pr[k] = wr[k].x * hv0 + wr[k].y * hv1 + wr[k].z * hv2 + wr[k].w * hv3;
    }
    #pragma unroll
    for (int m = 32; m >= 1; m >>= 1) {
      #pragma unroll
      for (int k = 0; k < RROWS; k++) {
        pz[k] += __shfl_xor(pz[k], m);
        pr[k] += __shfl_xor(pr[k], m);
      }
    }
    if (lane == 0) {
      #pragma unroll
      for (int k = 0; k < RROWS; k++) { redA[wv][k] = pz[k]; redA[wv][RROWS + k] = pr[k]; }
    }
    __syncthreads();
    if (tid < RROWS) {
      float u = redA[0][tid] + redA[1][tid] + redA[2][tid] + redA[3][tid];
      zs[tid] = sigmoidf_(bz_pre + u);
    } else if (tid < 2 * RROWS) {
      int k = tid - RROWS;
      float u = redA[0][tid] + redA[1][tid] + redA[2][tid] + redA[3][tid];
      float r = sigmoidf_(br_pre + u);
      float rh = r * hloc[k];
      __hip_atomic_store(&rhpack[r0 + k], pack_tv(t + 1, rh),
                         __ATOMIC_RELAXED, __HIP_MEMORY_SCOPE_AGENT);
    }

    // ================= round B: v = whh@(r*h), h_new =================
    float rv0, rv1, rv2, rv3;
    {
      const unsigned long long* rp = rhpack + j0;
      unsigned long long w0, w1, w2, w3;
      int it = 0;
      for (;;) {
        w0 = __hip_atomic_load(rp + 0, __ATOMIC_RELAXED, __HIP_MEMORY_SCOPE_AGENT);
        if ((w0 >> 32) == ex) break;
        if (++it > (1 << 20)) break;
        __builtin_amdgcn_s_sleep(2);
      }
      for (;;) {
        w1 = __hip_atomic_load(rp + 1, __ATOMIC_RELAXED, __HIP_MEMORY_SCOPE_AGENT);
        w2 = __hip_atomic_load(rp + 2, __ATOMIC_RELAXED, __HIP_MEMORY_SCOPE_AGENT);
        w3 = __hip_atomic_load(rp + 3, __ATOMIC_RELAXED, __HIP_MEMORY_SCOPE_AGENT);
        if (((w1 >> 32) == ex) & ((w2 >> 32) == ex) & ((w3 >> 32) == ex)) break;
        if (++it > (1 << 20)) break;
        __builtin_amdgcn_s_sleep(1);
      }
      rv0 = __uint_as_float((unsigned)w0);
      rv1 = __uint_as_float((unsigned)w1);
      rv2 = __uint_as_float((unsigned)w2);
      rv3 = __uint_as_float((unsigned)w3);
    }

    float ph[RROWS];
    #pragma unroll
    for (int k = 0; k < RROWS; k++)
      ph[k] = wh[k].x * rv0 + wh[k].y * rv1 + wh[k].z * rv2 + wh[k].w * rv3;
    #pragma unroll
    for (int m = 32; m >= 1; m >>= 1) {
      #pragma unroll
      for (int k = 0; k < RROWS; k++) ph[k] += __shfl_xor(ph[k], m);
    }
    if (lane == 0) {
      #pragma unroll
      for (int k = 0; k < RROWS; k++) redB[wv][k] = ph[k];
    }
    __syncthreads();
    if (tid < RROWS) {
      float v  = redB[0][tid] + redB[1][tid] + redB[2][tid] + redB[3][tid];
      float z  = zs[tid];
      float hk = hloc[tid];
      float hp_ = tanhf(a_pre + v);
      float hn = (1.0f - z) * hk + z * hp_;
      hloc[tid] = hn;
      __hip_atomic_store(&hpack[(size_t)(t + 1) * HDIM + r0 + tid], pack_tv(t + 2, hn),
                         __ATOMIC_RELAXED, __HIP_MEMORY_SCOPE_AGENT);
      hseq[(size_t)t * HDIM + r0 + tid] = hn;               // fp32 (refine)
      hseqb[(size_t)t * HDIM + r0 + tid] = f2bf(hn);        // bf16 (GEMM A)
    }
  }
}

// ---------------- logits GEMM (bf16 MFMA): 500 blocks x (256m x 64n), 2 blocks/CU ----------------
// Same K-order as before -> bitwise-identical logits. Epilogue also emits per-row tile max
// (over this block's 64 cols, bias included) to tilemax[m][block] for the light argmax.
__global__ __launch_bounds__(256, 2) void k_gemm(
    const unsigned short* __restrict__ Abf, const float* __restrict__ outw,
    const float* __restrict__ outb, float* __restrict__ out, float* __restrict__ tmax) {
  const int tid  = threadIdx.x;
  const int lane = tid & 63;
  const int wv   = tid >> 6;
  const int n0   = blockIdx.x * 64;
  const int rA   = lane & 15;
  const int kg   = lane >> 4;

  f32x4 acc[4][4];
  #pragma unroll
  for (int i = 0; i < 4; i++)
    #pragma unroll
    for (int j = 0; j < 4; j++) acc[i][j] = (f32x4){0.f, 0.f, 0.f, 0.f};

  const int mbase = wv * 64 + rA;

  for (int k0 = 0; k0 < HDIM; k0 += 32) {
    const int ks = k0 + kg * 8;
    short8 afr[4];
    #pragma unroll
    for (int mi = 0; mi < 4; mi++)
      afr[mi] = *(const short8*)(Abf + (size_t)(mbase + mi * 16) * HDIM + ks);

    short8 bfr[4];
    #pragma unroll
    for (int nj = 0; nj < 4; nj++) {
      const float* bp = outw + (size_t)(n0 + nj * 16 + rA) * HDIM + ks;
      float4 b0 = *(const float4*)(bp);
      float4 b1 = *(const float4*)(bp + 4);
      short8 s;
      s[0] = (short)f2bf_fast(b0.x); s[1] = (short)f2bf_fast(b0.y);
      s[2] = (short)f2bf_fast(b0.z); s[3] = (short)f2bf_fast(b0.w);
      s[4] = (short)f2bf_fast(b1.x); s[5] = (short)f2bf_fast(b1.y);
      s[6] = (short)f2bf_fast(b1.z); s[7] = (short)f2bf_fast(b1.w);
      bfr[nj] = s;
    }

    #pragma unroll
    for (int mi = 0; mi < 4; mi++)
      #pragma unroll
      for (int nj = 0; nj < 4; nj++)
        acc[mi][nj] = __builtin_amdgcn_mfma_f32_16x16x32_bf16(afr[mi], bfr[nj], acc[mi][nj], 0, 0, 0);
  }

  float bias[4];
  #pragma unroll
  for (int nj = 0; nj < 4; nj++) bias[nj] = outb[n0 + nj * 16 + rA];

  // C writes: m = wv*64 + mi*16 + kg*4 + r, n = n0 + nj*16 + rA
  #pragma unroll
  for (int mi = 0; mi < 4; mi++) {
    #pragma unroll
    for (int nj = 0; nj < 4; nj++) {
      #pragma unroll
      for (int r = 0; r < 4; r++) {
        int m = wv * 64 + mi * 16 + kg * 4 + r;
        out[(size_t)m * VDIM + n0 + nj * 16 + rA] = acc[mi][nj][r] + bias[nj];
      }
    }
  }

  // tile-max epilogue: per row, max over this block's 64 cols (shfl over rA bits only —
  // masks 1/2/4/8 stay within the 16-lane rA group, kg bits untouched)
  #pragma unroll
  for (int mi = 0; mi < 4; mi++) {
    #pragma unroll
    for (int r = 0; r < 4; r++) {
      float mx = acc[mi][0][r] + bias[0];
      mx = fmaxf(mx, acc[mi][1][r] + bias[1]);
      mx = fmaxf(mx, acc[mi][2][r] + bias[2]);
      mx = fmaxf(mx, acc[mi][3][r] + bias[3]);
      mx = fmaxf(mx, __shfl_xor(mx, 1));
      mx = fmaxf(mx, __shfl_xor(mx, 2));
      mx = fmaxf(mx, __shfl_xor(mx, 4));
      mx = fmaxf(mx, __shfl_xor(mx, 8));
      if (rA == 0) {
        int m = wv * 64 + mi * 16 + kg * 4 + r;
        tmax[(size_t)m * TMSTR + blockIdx.x] = mx;
      }
    }
  }
}

// ---------------- light argmax: tile-max prune + fp32 refinement ----------------
__global__ __launch_bounds__(256) void k_argmax(const float* __restrict__ logits,
                                                const float* __restrict__ tmax,
                                                const float* __restrict__ hseqf,
                                                const float* __restrict__ outw,
                                                const float* __restrict__ outb,
                                                float* __restrict__ outids) {
  const int t = blockIdx.x;
  const int tid = threadIdx.x;
  const float* row = logits + (size_t)t * VDIM;

  __shared__ float tm[NBN];
  for (int q = tid; q < NBN; q += 256) tm[q] = tmax[(size_t)t * TMSTR + q];
  __syncthreads();

  // row max from tile maxes (exact: tilemax computed from the same stored logits)
  float mx = -3.4e38f;
  for (int q = tid; q < NBN; q += 256) mx = fmaxf(mx, tm[q]);
  __shared__ float sm[256];
  sm[tid] = mx;
  __syncthreads();
  for (int s = 128; s > 0; s >>= 1) {
    if (tid < s) sm[tid] = fmaxf(sm[tid], sm[tid + s]);
    __syncthreads();
  }
  const float bmax = sm[0];
  const float cut = bmax - 0.25f;
  __syncthreads();

  // qualifying tiles
  __shared__ int qlist[64];
  __shared__ int qn;
  if (tid == 0) qn = 0;
  __syncthreads();
  for (int q = tid; q < NBN; q += 256) {
    if (tm[q] >= cut) {
      int p = atomicAdd(&qn, 1);
      if (p < 64) qlist[p] = q;
    }
  }
  __syncthreads();

  __shared__ int cand[64];
  __shared__ int cnt;
  if (tid == 0) cnt = 0;
  __syncthreads();
  if (qn <= 64) {
    // scan only qualifying tiles (typically 1-3): 4 tiles per pass, one per wave
    const int nq = qn;
    for (int p = 0; p < nq; p += 4) {
      int sl = p + (tid >> 6);
      if (sl < nq) {
        int v = qlist[sl] * 64 + (tid & 63);
        if (row[v] >= cut) {
          int c = atomicAdd(&cnt, 1);
          if (c < 64) cand[c] = v;
        }
      }
    }
  } else {
    // pathological fallback: full-row scan (identical to prior rounds' behavior)
    for (int v = tid; v < VDIM; v += 256) {
      if (row[v] >= cut) {
        int c = atomicAdd(&cnt, 1);
        if (c < 64) cand[c] = v;
      }
    }
  }
  __syncthreads();
  int n = cnt < 64 ? cnt : 64;

  // exact fp32 recompute of candidates; first-index tie rule (matches jnp.argmax)
  __shared__ float cval[64];
  if (tid < n) {
    int v = cand[tid];
    const float* w = outw + (size_t)v * HDIM;
    const float* h = hseqf + (size_t)t * HDIM;
    float s0 = 0.f, s1 = 0.f, s2 = 0.f, s3 = 0.f;
    for (int k = 0; k < HDIM; k += 4) {
      float4 wf = *(const float4*)(w + k);
      float4 hf = *(const float4*)(h + k);
      s0 += wf.x * hf.x; s1 += wf.y * hf.y; s2 += wf.z * hf.z; s3 += wf.w * hf.w;
    }
    cval[tid] = (s0 + s1) + (s2 + s3) + outb[v];
  }
  __syncthreads();
  if (tid == 0) {
    float best = -3.4e38f; int bi = 0x7FFFFFFF;
    for (int i = 0; i < n; i++) {
      float v = cval[i]; int id = cand[i];
      if (v > best || (v == best && id < bi)) { best = v; bi = id; }
    }
    outids[t] = (float)bi;
  }
}

// ---------------- launch ----------------
extern "C" void kernel_launch(void* const* d_in, const int* in_sizes, int n_in,
                              void* d_out, int out_size, void* d_ws, size_t ws_size,
                              hipStream_t stream) {
  (void)in_sizes; (void)n_in; (void)out_size; (void)ws_size;
  const float* enc    = (const float*)d_in[0];
  const int*   tokens = (const int*)d_in[1];
  const float* emb    = (const float*)d_in[2];
  const float* wzx_w  = (const float*)d_in[3];
  const float* wzx_b  = (const float*)d_in[4];
  const float* wrx_w  = (const float*)d_in[5];
  const float* wrx_b  = (const float*)d_in[6];
  const float* whx_w  = (const float*)d_in[7];
  const float* whx_b  = (const float*)d_in[8];
  const float* wzh_w  = (const float*)d_in[9];
  const float* wzh_b  = (const float*)d_in[10];
  const float* wrh_w  = (const float*)d_in[11];
  const float* wrh_b  = (const float*)d_in[12];
  const float* whh_w  = (const float*)d_in[13];
  const float* whh_b  = (const float*)d_in[14];
  const float* out_w  = (const float*)d_in[15];
  const float* out_b  = (const float*)d_in[16];
  float* ws  = (float*)d_ws;
  float* out = (float*)d_out;

  k_pre<<<dim3(192 + T_STEPS + 2), dim3(256), 0, stream>>>(
      enc, tokens, emb, wzx_w, wrx_w, whx_w,
      wzx_b, wzh_b, wrx_b, wrh_b, whx_b, whh_b, ws);
  k_recur<<<dim3(RG), dim3(256), 0, stream>>>(wzh_w, wrh_w, whh_w, ws);
  k_gemm<<<dim3(NBN), dim3(256), 0, stream>>>((const unsigned short*)(ws + WS_HSEQB),
                                              out_w, out_b, out, ws + WS_TMAX);
  k_argmax<<<dim3(T_STEPS), dim3(256), 0, stream>>>(out, ws + WS_TMAX, ws + WS_HSEQ,
                                                    out_w, out_b,
                                                    out + (size_t)T_STEPS * VDIM);
}